// Round 15
// baseline (120.480 us; speedup 1.0000x reference)
//
#include <hip/hip_runtime.h>
#include <math.h>

#define BS 32
#define NA 8400
#define NM 64
#define NC 80
#define BA (BS*NA)          // 268800 anchors total
#define NSLOTS 640          // 64 gts * 10 claim slots
#define GRID 4096           // 2048 topk+store blocks + 2048 store-only blocks

// ---- CIoU exactly mirroring the reference (b1 = gt, b2 = pred), clipped at 0
__device__ __forceinline__ float ciou_clip(float g0,float g1,float g2,float g3,
                                           float p0,float p1,float p2,float p3){
    const float eps = 1e-7f;
    float w1 = g2-g0, h1 = (g3-g1)+eps;
    float w2 = p2-p0, h2 = (p3-p1)+eps;
    float iw = fminf(g2,p2)-fmaxf(g0,p0);
    float ih = fminf(g3,p3)-fmaxf(g1,p1);
    float inter = fmaxf(iw,0.f)*fmaxf(ih,0.f);
    float uni = w1*h1 + w2*h2 - inter + eps;
    float iou = inter/uni;
    float cw = fmaxf(g2,p2)-fminf(g0,p0);
    float ch = fmaxf(g3,p3)-fminf(g1,p1);
    float c2 = cw*cw + ch*ch + eps;
    float dx = p0+p2-g0-g2;
    float dy = p1+p3-g1-g3;
    float rho2 = (dx*dx + dy*dy)*0.25f;
    float dat = atanf(w2/h2) - atanf(w1/h1);
    float v = 0.40528473f * (dat*dat);     // 4/pi^2
    float alpha = v/((v - iou) + (1.f + eps));
    float c = iou - (rho2/c2 + v*alpha);
    return fmaxf(c, 0.f);
}

// ---- sparse fixup writer (fg anchor): 5 scalars + bbox + one score element
__device__ __forceinline__ void writefix(
    float* __restrict__ out, int b, int a, int m, float align,
    const unsigned* s_pa, const unsigned* s_po,
    const int* __restrict__ gt_labels, const float* __restrict__ gt_bboxes)
{
    size_t i = (size_t)b*NA + a;
    float norm = align * __uint_as_float(s_po[m])
               / (__uint_as_float(s_pa[m]) + 1e-9f);
    int lab = gt_labels[b*NM + m];
    out[i] = (float)lab;                                             // target_labels
    *(float4*)&out[(size_t)BA + i*4] =
        *(const float4*)&gt_bboxes[(b*NM + m)*4];                    // target_bboxes
    out[(size_t)BA*85 + i] = 1.f;                                    // fg_mask
    out[(size_t)BA*86 + i] = (float)m;                               // target_gt_idx
    out[(size_t)BA*5 + i*NC + lab] = norm;                           // one-hot element
}

// ---- pass 1: blocks 0..2047 = topk for one gt + contiguous chunk of the zero
// region; blocks 2048..4095 = store-only (chunk + labels/bboxes broadcast).
// Roles are CONSECUTIVE block ranges -> blk%8 (XCD) uniform within each role
// (R14 lesson: interleaved roles pile one role onto 2 XCDs).
__global__ __launch_bounds__(256) void k_main(
    const float* __restrict__ pd_scores, const float* __restrict__ pd_bboxes,
    const int* __restrict__ gt_labels, const float* __restrict__ gt_bboxes,
    const float* __restrict__ mask_gt,
    int4* __restrict__ sel, int* __restrict__ sel_cnt,
    float* __restrict__ out)
{
    __shared__ float s_met[256];
    __shared__ int   s_idx[256];
    __shared__ unsigned s_nsel;
    int blk = blockIdx.x;
    int t = threadIdx.x;
    bool topk_blk = (blk < BS*NM);

    // ---- topk preamble: ISSUE the scattered gathers first (hidden under stores)
    int b = 0, m = 0, gt = 0;
    bool active = false, inGt = false;
    float4 g = make_float4(0.f,0.f,0.f,0.f);
    float4 p4 = make_float4(0.f,0.f,0.f,0.f);
    float sc = 0.f;
    int aidx = 0x7fffffff;
    int tot = 0;
    if (topk_blk){
        int xcd  = blk & 7;              // consecutive blocks -> blk%8 == XCD
        int slot = blk >> 3;             // 0..255
        b = xcd*4 + (slot >> 6);         // 4 images per XCD
        m = slot & 63;
        gt = b*NM + m;
        active = (mask_gt[gt] > 0.f);
        if (t == 0) s_nsel = 0u;
        if (active){
            g = *(const float4*)&gt_bboxes[(size_t)gt*4];
            int lab = gt_labels[gt];
            const float* pb = pd_bboxes + (size_t)b*NA*4;
            const float* ps = pd_scores + (size_t)b*NA*NC + lab;
            const float sinv[3] = {0.125f, 0.0625f, 0.03125f};
            const float sval[3] = {8.f, 16.f, 32.f};
            const int   nlvl[3] = {80, 40, 20};
            const int   aoff[3] = {0, 6400, 8000};
            int xlo[3], xcnt[3], ylo[3], cbase[3];
            #pragma unroll
            for (int l = 0; l < 3; ++l){
                float inv = sinv[l]; int n = nlvl[l];
                int x0 = max(0,   (int)floorf(g.x*inv - 0.5f));
                int x1 = min(n-1, (int)ceilf (g.z*inv - 0.5f));
                int y0 = max(0,   (int)floorf(g.y*inv - 0.5f));
                int y1 = min(n-1, (int)ceilf (g.w*inv - 0.5f));
                xlo[l] = x0; ylo[l] = y0;
                xcnt[l] = max(0, x1-x0+1);
                int yc  = max(0, y1-y0+1);
                cbase[l] = tot;
                tot += xcnt[l]*yc;
            }
            if (t < tot){
                int l = (t >= cbase[1]) + (t >= cbase[2]);
                int r = t - cbase[l];
                int cy = r / xcnt[l], cx = r - cy*xcnt[l];
                int gx = xlo[l] + cx, gy = ylo[l] + cy;
                float st = sval[l];
                float ax = (gx + 0.5f)*st, ay = (gy + 0.5f)*st;
                float dmin = fminf(fminf(ax-g.x, ay-g.y), fminf(g.z-ax, g.w-ay));
                if (dmin > 1e-9f){           // exact mask_in_gts
                    int a = aoff[l] + gy*nlvl[l] + gx;
                    p4 = *(const float4*)&pb[(size_t)a*4];    // issued here...
                    sc = ps[(size_t)a*NC];                    // ...hidden under stores
                    aidx = a; inGt = true;
                }
            }
        }
    }

    // ---- contiguous-chunk store of the zero region [BA*5, BA*87): 88.2 MB.
    // Each block owns one contiguous 21.5 KB span (fill-kernel pattern).
    {
        const int Z4 = (82*BA)/4;                 // 5,510,400 float4
        const int CZ = (Z4 + GRID - 1)/GRID;      // 1346 per block
        const float4 z4 = make_float4(0.f,0.f,0.f,0.f);
        float4* z = (float4*)(out + (size_t)BA*5);
        int s0 = blk*CZ, s1 = min(Z4, s0 + CZ);
        for (int e = s0 + t; e < s1; e += 256) z[e] = z4;
    }
    // ---- labels/bboxes broadcast (5.4 MB): store-only blocks, <=2 stores/thread
    if (!topk_blk){
        int e = (blk - BS*NM)*256 + t;            // 0..524287
        if (e < BA/4){                             // target_labels
            int bb = e / (NA/4);
            float v = (float)gt_labels[bb*NM];
            ((float4*)out)[e] = make_float4(v,v,v,v);
        }
        if (e < BA){                               // target_bboxes
            int bb = e / NA;
            ((float4*)(out + (size_t)BA))[e] = *(const float4*)&gt_bboxes[(size_t)bb*NM*4];
        }
        return;
    }

    // ---- metric + single-pass rank selection (exact jax.lax.top_k semantics)
    if (!active){
        if (t == 0) sel_cnt[gt] = 0;
        return;
    }
    float met = -1.f, ov = 0.f;
    if (inGt){
        float o = ciou_clip(g.x,g.y,g.z,g.w, p4.x,p4.y,p4.z,p4.w);
        met = sc * o; ov = o;
    }
    if (t < tot){ s_met[t] = met; s_idx[t] = aidx; }
    __syncthreads();

    if (inGt){
        int rank = 0, np = 0, P = 0;
        for (int j = 0; j < tot; ++j){
            float mj = s_met[j]; int ij = s_idx[j];
            bool pos = (mj > 0.f);
            P    += pos;
            rank += (mj > met || (mj == met && ij < aidx));
            np   += (pos && (ij < aidx));
        }
        bool claim;
        if (met > 0.f) claim = (rank < 10);
        else           claim = (P < 10) && ((aidx - np) < (10 - P));  // zero-fill rule
        if (claim){          // <=10 claims -> 16-slot stride is safe
            unsigned sl = atomicAdd(&s_nsel, 1u);
            sel[((size_t)gt<<4) + sl] =
                make_int4(aidx, __float_as_int(met), __float_as_int(ov), 0);
        }
    }
    __syncthreads();
    if (t == 0) sel_cnt[gt] = (int)s_nsel;
}

// ---- pass 2: one 256-thread block per image; O(NSLOTS^2) LDS dedup (~10 KB
// LDS, proven bit-exact as R13's phase E), pos maxima in LDS, sparse fixups.
__global__ __launch_bounds__(256) void k_assign(
    const float* __restrict__ pd_scores, const float* __restrict__ pd_bboxes,
    const int* __restrict__ gt_labels, const float* __restrict__ gt_bboxes,
    const int4* __restrict__ sel, const int* __restrict__ sel_cnt,
    float* __restrict__ out)
{
    __shared__ int   sa_a[NSLOTS];
    __shared__ float sa_met[NSLOTS];
    __shared__ float sa_ov[NSLOTS];
    __shared__ unsigned s_pa[NM], s_po[NM];
    int b = blockIdx.x;
    int t = threadIdx.x;

    for (int j = t; j < NSLOTS; j += 256){
        int gg = j/10, s2 = j - gg*10;
        int c = sel_cnt[b*NM + gg];
        if (s2 < c){
            int4 e = sel[((size_t)(b*NM + gg) << 4) + s2];
            sa_a[j] = e.x; sa_met[j] = __int_as_float(e.y); sa_ov[j] = __int_as_float(e.z);
        } else sa_a[j] = -1;
    }
    if (t < NM){ s_pa[t] = 0u; s_po[t] = 0u; }
    __syncthreads();

    int   r_a[3], r_m[3]; float r_al[3];
    #pragma unroll
    for (int q = 0; q < 3; ++q){
        int j = t + q*256;
        r_a[q] = -1;
        if (j < NSLOTS){
            int A = sa_a[j];
            if (A >= 0){
                int cnt = 0, firstk = j;
                for (int k = 0; k < NSLOTS; ++k){
                    if (sa_a[k] == A){ cnt++; if (k < firstk) firstk = k; }
                }
                if (firstk == j){                 // dedup owner (min gt slot)
                    int mm; float al, ovv;
                    if (cnt == 1){
                        mm = j/10; al = sa_met[j]; ovv = sa_ov[j];
                    } else {
                        // jnp.argmax over ALL 64 gts of clipped ciou (first max)
                        float4 p = *(const float4*)&pd_bboxes[((size_t)b*NA + A)*4];
                        float best = -1.f; int bm = 0;
                        for (int g2 = 0; g2 < NM; ++g2){
                            float4 gg4 = *(const float4*)&gt_bboxes[(b*NM + g2)*4];
                            float o = ciou_clip(gg4.x,gg4.y,gg4.z,gg4.w, p.x,p.y,p.z,p.w);
                            if (o > best){ best = o; bm = g2; }
                        }
                        mm = bm; ovv = best;
                        al = pd_scores[((size_t)b*NA + A)*NC + gt_labels[b*NM + mm]] * ovv;
                    }
                    atomicMax(&s_pa[mm], __float_as_uint(al));
                    atomicMax(&s_po[mm], __float_as_uint(ovv));
                    r_a[q] = A; r_m[q] = mm; r_al[q] = al;
                }
            }
        }
    }
    __syncthreads();                 // pos maxima final before norm reads
    #pragma unroll
    for (int q = 0; q < 3; ++q){
        if (r_a[q] >= 0)
            writefix(out, b, r_a[q], r_m[q], r_al[q], s_pa, s_po,
                     gt_labels, gt_bboxes);
    }
}

extern "C" void kernel_launch(void* const* d_in, const int* in_sizes, int n_in,
                              void* d_out, int out_size, void* d_ws, size_t ws_size,
                              hipStream_t stream) {
    const float* pd_scores = (const float*)d_in[0];
    const float* pd_bboxes = (const float*)d_in[1];
    const int*   gt_labels = (const int*)d_in[3];
    const float* gt_bboxes = (const float*)d_in[4];
    const float* mask_gt   = (const float*)d_in[5];
    float* out = (float*)d_out;

    // workspace: dense per-gt claim lists only (~520 KB, fully written each call)
    int4* sel     = (int4*)d_ws;                 // 2048 * 16 int4
    int*  sel_cnt = (int*)(sel + (size_t)BS*NM*16);  // 2048

    k_main<<<GRID, 256, 0, stream>>>(pd_scores, pd_bboxes, gt_labels, gt_bboxes,
                                     mask_gt, sel, sel_cnt, out);
    k_assign<<<BS, 256, 0, stream>>>(pd_scores, pd_bboxes, gt_labels, gt_bboxes,
                                     sel, sel_cnt, out);
}

// Round 16
// 27.834 us; speedup vs baseline: 4.3286x; 4.3286x over previous
//
#include <hip/hip_runtime.h>
#include <math.h>

#define BS 32
#define NA 8400
#define NM 64
#define NC 80
#define BA (BS*NA)          // 268800 anchors total
#define KAT 1024            // k_assign block size
#define GRID 4096           // k_main grid: 2048 topk blocks + 2048 store-only blocks

// ---- CIoU exactly mirroring the reference (b1 = gt, b2 = pred), clipped at 0
__device__ __forceinline__ float ciou_clip(float g0,float g1,float g2,float g3,
                                           float p0,float p1,float p2,float p3){
    const float eps = 1e-7f;
    float w1 = g2-g0, h1 = (g3-g1)+eps;
    float w2 = p2-p0, h2 = (p3-p1)+eps;
    float iw = fminf(g2,p2)-fmaxf(g0,p0);
    float ih = fminf(g3,p3)-fmaxf(g1,p1);
    float inter = fmaxf(iw,0.f)*fmaxf(ih,0.f);
    float uni = w1*h1 + w2*h2 - inter + eps;
    float iou = inter/uni;
    float cw = fmaxf(g2,p2)-fminf(g0,p0);
    float ch = fmaxf(g3,p3)-fminf(g1,p1);
    float c2 = cw*cw + ch*ch + eps;
    float dx = p0+p2-g0-g2;
    float dy = p1+p3-g1-g3;
    float rho2 = (dx*dx + dy*dy)*0.25f;
    float dat = atanf(w2/h2) - atanf(w1/h1);
    float v = 0.40528473f * (dat*dat);     // 4/pi^2
    float alpha = v/((v - iou) + (1.f + eps));
    float c = iou - (rho2/c2 + v*alpha);
    return fmaxf(c, 0.f);
}

// ---- sparse fixup writer (fg anchor): 5 scalars + bbox + one score element
__device__ __forceinline__ void writefix(
    float* __restrict__ out, int b, int a, int m, float align,
    const unsigned* s_pa, const unsigned* s_po,
    const int* __restrict__ gt_labels, const float* __restrict__ gt_bboxes)
{
    size_t i = (size_t)b*NA + a;
    float norm = align * __uint_as_float(s_po[m])
               / (__uint_as_float(s_pa[m]) + 1e-9f);
    int lab = gt_labels[b*NM + m];
    out[i] = (float)lab;                                             // target_labels
    *(float4*)&out[(size_t)BA + i*4] =
        *(const float4*)&gt_bboxes[(b*NM + m)*4];                    // target_bboxes
    out[(size_t)BA*85 + i] = 1.f;                                    // fg_mask
    out[(size_t)BA*86 + i] = (float)m;                               // target_gt_idx
    out[(size_t)BA*5 + i*NC + lab] = norm;                           // one-hot element
}

// ---- pass 1 (R10 structure): blocks 0..2047 = topk for one gt + store share;
// blocks 2048..4095 = store-only. ONE change vs R10: the 88.2 MB zero region
// [BA*5, BA*87) is written as per-block CONTIGUOUS chunks (fill-kernel pattern)
// instead of 16MB-stride grid-stride.
__global__ __launch_bounds__(256) void k_main(
    const float* __restrict__ pd_scores, const float* __restrict__ pd_bboxes,
    const int* __restrict__ gt_labels, const float* __restrict__ gt_bboxes,
    const float* __restrict__ mask_gt,
    int4* __restrict__ sel, int* __restrict__ sel_cnt,
    float* __restrict__ out)
{
    __shared__ float s_met[256];
    __shared__ int   s_idx[256];
    __shared__ unsigned s_nsel;
    int blk  = blockIdx.x;
    int t = threadIdx.x;
    bool topk_blk = (blk < BS*NM);

    // XCD swizzle (topk blocks): all 64 gts of one image land on one XCD
    int b = 0, m = 0, gt = 0;
    bool active = false;
    if (topk_blk){
        int xcd  = blk & 7;
        int slot = blk >> 3;             // 0..255
        b = xcd*4 + (slot >> 6);         // 4 images per XCD
        m = slot & 63;
        gt = b*NM + m;
        active = (mask_gt[gt] > 0.f);
        if (t == 0) s_nsel = 0u;
    }

    // ---- gt candidate setup + ISSUE the scattered loads (registers p4, sc)
    float4 g = make_float4(0.f,0.f,0.f,0.f);
    float4 p4 = make_float4(0.f,0.f,0.f,0.f);
    float sc = 0.f;
    int aidx = 0x7fffffff;
    bool inGt = false;
    int tot = 0;
    if (active){
        g = *(const float4*)&gt_bboxes[(size_t)gt*4];
        int lab = gt_labels[gt];
        const float* pb = pd_bboxes + (size_t)b*NA*4;
        const float* ps = pd_scores + (size_t)b*NA*NC + lab;
        const float sinv[3] = {0.125f, 0.0625f, 0.03125f};
        const float sval[3] = {8.f, 16.f, 32.f};
        const int   nlvl[3] = {80, 40, 20};
        const int   aoff[3] = {0, 6400, 8000};
        int xlo[3], xcnt[3], ylo[3], cbase[3];
        #pragma unroll
        for (int l = 0; l < 3; ++l){
            float inv = sinv[l]; int n = nlvl[l];
            int x0 = max(0,   (int)floorf(g.x*inv - 0.5f));
            int x1 = min(n-1, (int)ceilf (g.z*inv - 0.5f));
            int y0 = max(0,   (int)floorf(g.y*inv - 0.5f));
            int y1 = min(n-1, (int)ceilf (g.w*inv - 0.5f));
            xlo[l] = x0; ylo[l] = y0;
            xcnt[l] = max(0, x1-x0+1);
            int yc  = max(0, y1-y0+1);
            cbase[l] = tot;
            tot += xcnt[l]*yc;
        }
        if (t < tot){
            int l = (t >= cbase[1]) + (t >= cbase[2]);
            int r = t - cbase[l];
            int cy = r / xcnt[l], cx = r - cy*xcnt[l];
            int gx = xlo[l] + cx, gy = ylo[l] + cy;
            float st = sval[l];
            float ax = (gx + 0.5f)*st, ay = (gy + 0.5f)*st;
            float dmin = fminf(fminf(ax-g.x, ay-g.y), fminf(g.z-ax, g.w-ay));
            if (dmin > 1e-9f){           // exact mask_in_gts
                int a = aoff[l] + gy*nlvl[l] + gx;
                p4 = *(const float4*)&pb[(size_t)a*4];    // issued here...
                sc = ps[(size_t)a*NC];                    // ...latency hidden below
                aidx = a; inGt = true;
            }
        }
    }

    // ---- zero region [BA*5, BA*87): per-block contiguous chunk (fill pattern)
    {
        const int Z4 = (82*BA)/4;                 // 5,510,400 float4
        const int CZ = (Z4 + GRID - 1)/GRID;      // 1346 per block (21.5 KB)
        const float4 z4 = make_float4(0.f,0.f,0.f,0.f);
        float4* z = (float4*)(out + (size_t)BA*5);
        int s0 = blk*CZ, s1 = min(Z4, s0 + CZ);
        for (int e = s0 + t; e < s1; e += 256) z[e] = z4;
    }
    // ---- labels/bboxes broadcast (5.4 MB): grid-stride, as in R10
    {
        int tid = blk*256 + t;
        const int stride = GRID*256;
        float4* b4 = (float4*)(out + (size_t)BA);        // target_bboxes: gt[b,0]
        for (int e = tid; e < BA; e += stride){
            int bb = e / NA;
            b4[e] = *(const float4*)&gt_bboxes[(size_t)bb*NM*4];
        }
        float4* l4 = (float4*)out;                        // target_labels: gt_labels[b,0]
        for (int e = tid; e < BA/4; e += stride){
            int bb = e / (NA/4);
            float v = (float)gt_labels[bb*NM];
            l4[e] = make_float4(v,v,v,v);
        }
    }

    // ---- metric + single-pass rank selection (exact jax.lax.top_k semantics)
    if (!topk_blk) return;
    if (!active){
        if (t == 0) sel_cnt[gt] = 0;
        return;
    }
    float met = -1.f, ov = 0.f;
    if (inGt){
        float o = ciou_clip(g.x,g.y,g.z,g.w, p4.x,p4.y,p4.z,p4.w);
        met = sc * o; ov = o;
    }
    if (t < tot){ s_met[t] = met; s_idx[t] = aidx; }
    __syncthreads();

    if (inGt){
        int rank = 0, np = 0, P = 0;
        for (int j = 0; j < tot; ++j){
            float mj = s_met[j]; int ij = s_idx[j];
            bool pos = (mj > 0.f);
            P    += pos;
            rank += (mj > met || (mj == met && ij < aidx));
            np   += (pos && (ij < aidx));
        }
        bool claim;
        if (met > 0.f){
            claim = (rank < 10);
        } else {            // met == 0 candidate: zero-fill slot test
            claim = (P < 10) && ((aidx - np) < (10 - P));
        }
        if (claim){          // <=10 claims -> 16-slot stride is safe
            unsigned sl = atomicAdd(&s_nsel, 1u);
            sel[((size_t)gt<<4) + sl] =
                make_int4(aidx, __float_as_int(met), __float_as_int(ov), 0);
        }
    }
    __syncthreads();
    if (t == 0) sel_cnt[gt] = (int)s_nsel;
}

// ---- pass 2 (R10-verbatim): ONE BLOCK PER IMAGE, 1024 threads. Dense LDS
// count/min; multi-claim anchors resolved ONE WAVE PER ANCHOR with
// lane-parallel gts (R15 lesson: per-thread serial 64-gt atanf loops under
// divergence serialize catastrophically — 124 µs vs ~4 µs).
__global__ __launch_bounds__(KAT) void k_assign(
    const float* __restrict__ pd_scores, const float* __restrict__ pd_bboxes,
    const int* __restrict__ gt_labels, const float* __restrict__ gt_bboxes,
    const int4* __restrict__ sel, const int* __restrict__ sel_cnt,
    float* __restrict__ out)
{
    __shared__ unsigned s_cnt[NA];       // claim count per anchor (33.6 KB)
    __shared__ unsigned s_min[NA];       // min claiming gt per anchor (33.6 KB)
    __shared__ unsigned s_pa[NM], s_po[NM];   // pos_align / pos_overlaps (uint max)
    __shared__ int  s_mn;
    __shared__ int4 s_multi[320];        // {a, m*, align_bits, done}; cap 640/2
    int b = blockIdx.x;
    int t = threadIdx.x;

    for (int j = t; j < NA; j += KAT){ s_cnt[j] = 0u; s_min[j] = 0xffffffffu; }
    if (t < NM){ s_pa[t] = 0u; s_po[t] = 0u; }
    if (t == 0) s_mn = 0;
    __syncthreads();

    // phase 1: load this thread's claim entry (64 gts x 16 slots == 1024 threads)
    int gt = t >> 4, slotn = t & 15;
    bool has = false; int a = 0; float met = 0.f, ov = 0.f;
    if (slotn < sel_cnt[b*NM + gt]){
        int4 e = sel[((size_t)(b*NM + gt) << 4) + slotn];
        a = e.x; met = __int_as_float(e.y); ov = __int_as_float(e.z);
        has = true;
        atomicAdd(&s_cnt[a], 1u);
        atomicMin(&s_min[a], (unsigned)gt);
    }
    __syncthreads();

    // phase 2a: single-claim anchors -> pos maxima; multi-claim -> dedup'd list
    unsigned c = 0;
    if (has){
        c = s_cnt[a];
        if (c == 1u){
            atomicMax(&s_pa[gt], __float_as_uint(met));
            atomicMax(&s_po[gt], __float_as_uint(ov));
        } else if (s_min[a] == (unsigned)gt){   // exactly one entry per multi anchor
            int k = atomicAdd(&s_mn, 1);
            s_multi[k] = make_int4(a, 0, 0, 0);
        }
    }
    __syncthreads();

    // phase 2b: one wave per multi anchor; lane mm = gt mm (jnp.argmax: first max)
    int wv = t >> 6, lane = t & 63;
    for (int k = wv; k < s_mn; k += KAT/64){
        int aa = s_multi[k].x;
        float4 p = *(const float4*)&pd_bboxes[((size_t)b*NA + aa)*4]; // broadcast
        float4 g = *(const float4*)&gt_bboxes[(b*NM + lane)*4];
        float o = ciou_clip(g.x,g.y,g.z,g.w, p.x,p.y,p.z,p.w);
        float bv = o; int bi = lane;
        #pragma unroll
        for (int d = 1; d < 64; d <<= 1){
            float o2 = __shfl_xor(bv, d);
            int   i2 = __shfl_xor(bi, d);
            if (o2 > bv || (o2 == bv && i2 < bi)){ bv = o2; bi = i2; }
        }
        if (lane == bi){                 // unique winner lane
            int lab = gt_labels[b*NM + bi];
            float al = pd_scores[((size_t)b*NA + aa)*NC + lab] * bv;
            atomicMax(&s_pa[bi], __float_as_uint(al));
            atomicMax(&s_po[bi], __float_as_uint(bv));
            s_multi[k] = make_int4(aa, bi, __float_as_int(al), 1);
        }
    }
    __syncthreads();

    // phase 3: pos arrays final -> write all fg fixups
    if (has && c == 1u)
        writefix(out, b, a, gt, met, s_pa, s_po, gt_labels, gt_bboxes);
    if (t < s_mn){
        int4 mm = s_multi[t];
        writefix(out, b, mm.x, mm.y, __int_as_float(mm.z), s_pa, s_po,
                 gt_labels, gt_bboxes);
    }
}

extern "C" void kernel_launch(void* const* d_in, const int* in_sizes, int n_in,
                              void* d_out, int out_size, void* d_ws, size_t ws_size,
                              hipStream_t stream) {
    const float* pd_scores = (const float*)d_in[0];
    const float* pd_bboxes = (const float*)d_in[1];
    const int*   gt_labels = (const int*)d_in[3];
    const float* gt_bboxes = (const float*)d_in[4];
    const float* mask_gt   = (const float*)d_in[5];
    float* out = (float*)d_out;

    // workspace: dense per-gt claim lists only (~520 KB, fully written each call)
    int4* sel     = (int4*)d_ws;                 // 2048 * 16 int4
    int*  sel_cnt = (int*)(sel + (size_t)BS*NM*16);  // 2048

    k_main<<<GRID, 256, 0, stream>>>(pd_scores, pd_bboxes, gt_labels, gt_bboxes,
                                     mask_gt, sel, sel_cnt, out);
    k_assign<<<BS, KAT, 0, stream>>>(pd_scores, pd_bboxes, gt_labels, gt_bboxes,
                                     sel, sel_cnt, out);
}